// Round 1
// baseline (921.610 us; speedup 1.0000x reference)
//
#include <hip/hip_runtime.h>
#include <math.h>

#define HF 128
#define NL 128
#define NP 1024
#define NBATCH 4
#define JT 32
#define EPSF 1e-8f

__device__ __forceinline__ float silu_f(float x) { return x / (1.0f + __expf(-x)); }
__device__ __forceinline__ float sigmoid_f(float x) { return 1.0f / (1.0f + __expf(-x)); }

// ---------------------------------------------------------------------------
// Precompute per-node first-layer projections (bias folded where appropriate):
//   Al[bi][n] = h_ligand[bi]  @ aW1[0:128]   + ab1
//   Ap[bj][n] = h_protein[bj] @ aW1[128:256]
//   Vp[bj][n] = h_protein[bj] @ vW1[0:128]   + vb1
//   Cl[bi][n] = h_ligand[bi]  @ cW1[0:128]   + cb1
//   Cp[bj][n] = h_protein[bj] @ cW1[128:256]
// 8 rows per block, 128 threads (one output column each).
// ---------------------------------------------------------------------------
__global__ __launch_bounds__(128) void precompute_kernel(
    const float* __restrict__ h_ligand, const float* __restrict__ h_protein,
    const float* __restrict__ aW1, const float* __restrict__ ab1,
    const float* __restrict__ vW1, const float* __restrict__ vb1,
    const float* __restrict__ cW1, const float* __restrict__ cb1,
    float* __restrict__ Al, float* __restrict__ Ap, float* __restrict__ Vp,
    float* __restrict__ Cl, float* __restrict__ Cp)
{
    const int blk = blockIdx.x;
    const int n = threadIdx.x;
    const float* in; const float* W; const float* bias; float* out; int r0;
    if (blk < 64)        { r0 = blk*8;        in = h_ligand;  W = aW1;         bias = ab1;     out = Al; }
    else if (blk < 576)  { r0 = (blk-64)*8;   in = h_protein; W = aW1 + HF*HF; bias = nullptr; out = Ap; }
    else if (blk < 1088) { r0 = (blk-576)*8;  in = h_protein; W = vW1;         bias = vb1;     out = Vp; }
    else if (blk < 1152) { r0 = (blk-1088)*8; in = h_ligand;  W = cW1;         bias = cb1;     out = Cl; }
    else                 { r0 = (blk-1152)*8; in = h_protein; W = cW1 + HF*HF; bias = nullptr; out = Cp; }

    __shared__ float rows[8][HF];
    for (int idx = n; idx < 8*HF; idx += 128) rows[idx >> 7][idx & 127] = in[r0*HF + idx];
    __syncthreads();

    const float bv = bias ? bias[n] : 0.0f;
    float acc[8];
    #pragma unroll
    for (int r = 0; r < 8; ++r) acc[r] = bv;
    #pragma unroll 4
    for (int k = 0; k < HF; ++k) {
        float w = W[k*HF + n];
        #pragma unroll
        for (int r = 0; r < 8; ++r) acc[r] = fmaf(rows[r][k], w, acc[r]);
    }
    #pragma unroll
    for (int r = 0; r < 8; ++r) out[(r0 + r)*HF + n] = acc[r];
}

// ---------------------------------------------------------------------------
// Main fused kernel: one block per (b,i) ligand row; loops over 1024 protein j
// in tiles of 32.  Phase A: attention branch (aW2 GEMM + aW3 dot) and c-branch
// (x accumulation).  Phase B: value branch (vW2 GEMM) with h accumulation.
// ---------------------------------------------------------------------------
__device__ __forceinline__ void gemm_tile_32x128(
    const float* __restrict__ tile, const float* __restrict__ Wlds,
    int tj, int tn, float acc[4][4])
{
    for (int k = 0; k < HF; k += 4) {
        const float4 a0 = *(const float4*)&tile[(tj     )*HF + k];
        const float4 a1 = *(const float4*)&tile[(tj +  8)*HF + k];
        const float4 a2 = *(const float4*)&tile[(tj + 16)*HF + k];
        const float4 a3 = *(const float4*)&tile[(tj + 24)*HF + k];
        const float ar[4][4] = {{a0.x,a0.y,a0.z,a0.w},
                                {a1.x,a1.y,a1.z,a1.w},
                                {a2.x,a2.y,a2.z,a2.w},
                                {a3.x,a3.y,a3.z,a3.w}};
        #pragma unroll
        for (int kk = 0; kk < 4; ++kk) {
            const float4 w = *(const float4*)&Wlds[(k + kk)*HF + (tn << 2)];
            #pragma unroll
            for (int r = 0; r < 4; ++r) {
                acc[r][0] = fmaf(ar[r][kk], w.x, acc[r][0]);
                acc[r][1] = fmaf(ar[r][kk], w.y, acc[r][1]);
                acc[r][2] = fmaf(ar[r][kk], w.z, acc[r][2]);
                acc[r][3] = fmaf(ar[r][kk], w.w, acc[r][3]);
            }
        }
    }
}

__global__ __launch_bounds__(256) void egnn_main_kernel(
    const float* __restrict__ x_ligand, const float* __restrict__ x_protein,
    const float* __restrict__ ligand_mask, const float* __restrict__ protein_mask,
    const float* __restrict__ aW1, const float* __restrict__ aW2,
    const float* __restrict__ ab2, const float* __restrict__ aW3, const float* __restrict__ ab3,
    const float* __restrict__ vW1, const float* __restrict__ vW2, const float* __restrict__ vb2,
    const float* __restrict__ cW1, const float* __restrict__ cW2, const float* __restrict__ cb2,
    const float* __restrict__ Al, const float* __restrict__ Ap, const float* __restrict__ Vp,
    const float* __restrict__ Cl, const float* __restrict__ Cp,
    float* __restrict__ out)
{
    __shared__ __align__(16) float Wlds[HF*HF];     // 64 KB: aW2 then vW2
    __shared__ __align__(16) float tile[JT*HF];     // 16 KB: a1 or v tile
    __shared__ float attn_e[NP];                    // sigmoid(..)*pm*edge per j
    __shared__ float ds_all[NP];
    __shared__ float Al_i[HF], Cl_i[HF], aw1l[HF], cw1l[HF], vw1l[HF];
    __shared__ float ab2s[HF], aW3s[HF], cW2s[HF], vb2s[HF];
    __shared__ float dir_t[JT][3];
    __shared__ float edge_t[JT], pm_t[JT];
    __shared__ float hred[8*HF];
    __shared__ float xw[4][3];

    const int t = threadIdx.x;
    const int bi = blockIdx.x;
    const int b = bi >> 7, i = bi & (NL - 1);

    if (t < HF) {
        Al_i[t] = Al[(b*NL + i)*HF + t];
        Cl_i[t] = Cl[(b*NL + i)*HF + t];
        aw1l[t] = aW1[256*HF + t];
        cw1l[t] = cW1[256*HF + t];
        vw1l[t] = vW1[128*HF + t];
        ab2s[t] = ab2[t];
        aW3s[t] = aW3[t];
        cW2s[t] = cW2[t];
        vb2s[t] = vb2[t];
    }
    for (int idx = t; idx < HF*HF; idx += 256) Wlds[idx] = aW2[idx];

    const float xl0 = x_ligand[(b*NL + i)*3 + 0];
    const float xl1 = x_ligand[(b*NL + i)*3 + 1];
    const float xl2 = x_ligand[(b*NL + i)*3 + 2];
    const float ab3v = ab3[0];
    const float cb2v = cb2[0];

    const float* Ap_b = Ap + (size_t)b*NP*HF;
    const float* Cp_b = Cp + (size_t)b*NP*HF;
    const float* Vp_b = Vp + (size_t)b*NP*HF;
    const float* xp_b = x_protein + (size_t)b*NP*3;
    const float* pm_b = protein_mask + (size_t)b*NP;

    float xacc0 = 0.f, xacc1 = 0.f, xacc2 = 0.f;
    const int tj = t >> 5, tn = t & 31;      // GEMM mapping: rows tj+8r, cols tn*4..+3
    const int cjl = t >> 3, cg = t & 7;      // c-branch mapping

    __syncthreads();

    // ------------------------------ Phase A ------------------------------
    for (int jt = 0; jt < NP/JT; ++jt) {
        const int j0 = jt*JT;
        if (t < JT) {
            const int j = j0 + t;
            float r0 = xl0 - xp_b[j*3 + 0];
            float r1 = xl1 - xp_b[j*3 + 1];
            float r2 = xl2 - xp_b[j*3 + 2];
            float ds = r0*r0 + r1*r1 + r2*r2;
            float dist = sqrtf(ds + EPSF);
            float e = dist < 10.0f ? 1.0f : 0.0f;
            float inv = 1.0f / (dist + EPSF);
            ds_all[j] = ds;
            dir_t[t][0] = r0*inv; dir_t[t][1] = r1*inv; dir_t[t][2] = r2*inv;
            edge_t[t] = e;
            pm_t[t] = pm_b[j];
        }
        __syncthreads();

        // a1 = silu(Al_i + Ap[j] + ds*aw1_last)  (ab1 folded into Al_i)
        #pragma unroll
        for (int m = 0; m < 16; ++m) {
            int idx = m*256 + t;
            int jl = idx >> 7, n = idx & 127;
            float dsv = ds_all[j0 + jl];
            float v = Al_i[n] + Ap_b[(j0 + jl)*HF + n] + dsv*aw1l[n];
            tile[idx] = silu_f(v);
        }
        // c-branch: cw = tanh(silu(pre_c)@cW2 + cb2)*pm*edge; x += dir*cw
        {
            float dsv = ds_all[j0 + cjl];
            float part = 0.f;
            #pragma unroll
            for (int q = 0; q < 16; ++q) {
                int n = cg*16 + q;
                float v = Cl_i[n] + Cp_b[(j0 + cjl)*HF + n] + dsv*cw1l[n];
                part += silu_f(v) * cW2s[n];
            }
            part += __shfl_xor(part, 1);
            part += __shfl_xor(part, 2);
            part += __shfl_xor(part, 4);
            if (cg == 0) {
                float cw = tanhf(part + cb2v) * pm_t[cjl] * edge_t[cjl];
                xacc0 = fmaf(dir_t[cjl][0], cw, xacc0);
                xacc1 = fmaf(dir_t[cjl][1], cw, xacc1);
                xacc2 = fmaf(dir_t[cjl][2], cw, xacc2);
            }
        }
        __syncthreads();

        // a2 = silu(a1 @ aW2 + ab2); attn = sigmoid(a2 @ aW3 + ab3)*pm*edge
        float acc[4][4] = {{0.f}};
        gemm_tile_32x128(tile, Wlds, tj, tn, acc);
        #pragma unroll
        for (int r = 0; r < 4; ++r) {
            float p = 0.f;
            #pragma unroll
            for (int c = 0; c < 4; ++c) {
                int n = (tn << 2) + c;
                p += silu_f(acc[r][c] + ab2s[n]) * aW3s[n];
            }
            p += __shfl_xor(p, 1);
            p += __shfl_xor(p, 2);
            p += __shfl_xor(p, 4);
            p += __shfl_xor(p, 8);
            p += __shfl_xor(p, 16);
            if (tn == 0) {
                int jl = tj + 8*r;
                attn_e[j0 + jl] = sigmoid_f(p + ab3v) * pm_t[jl] * edge_t[jl];
            }
        }
        __syncthreads();
    }

    // swap weights: vW2
    for (int idx = t; idx < HF*HF; idx += 256) Wlds[idx] = vW2[idx];
    __syncthreads();

    // ------------------------------ Phase B ------------------------------
    float hp0 = 0.f, hp1 = 0.f, hp2 = 0.f, hp3 = 0.f;
    for (int jt = 0; jt < NP/JT; ++jt) {
        const int j0 = jt*JT;
        #pragma unroll
        for (int m = 0; m < 16; ++m) {
            int idx = m*256 + t;
            int jl = idx >> 7, n = idx & 127;
            float v = Vp_b[(j0 + jl)*HF + n] + ds_all[j0 + jl]*vw1l[n];
            tile[idx] = silu_f(v);
        }
        __syncthreads();

        float acc[4][4] = {{0.f}};
        gemm_tile_32x128(tile, Wlds, tj, tn, acc);
        #pragma unroll
        for (int r = 0; r < 4; ++r) {
            int jl = tj + 8*r;
            float ae = attn_e[j0 + jl];
            hp0 = fmaf(ae, acc[r][0] + vb2s[(tn << 2) + 0], hp0);
            hp1 = fmaf(ae, acc[r][1] + vb2s[(tn << 2) + 1], hp1);
            hp2 = fmaf(ae, acc[r][2] + vb2s[(tn << 2) + 2], hp2);
            hp3 = fmaf(ae, acc[r][3] + vb2s[(tn << 2) + 3], hp3);
        }
        __syncthreads();
    }

    // ---------------------------- Reductions -----------------------------
    hred[tj*HF + (tn << 2) + 0] = hp0;
    hred[tj*HF + (tn << 2) + 1] = hp1;
    hred[tj*HF + (tn << 2) + 2] = hp2;
    hred[tj*HF + (tn << 2) + 3] = hp3;

    xacc0 += __shfl_xor(xacc0, 1);  xacc1 += __shfl_xor(xacc1, 1);  xacc2 += __shfl_xor(xacc2, 1);
    xacc0 += __shfl_xor(xacc0, 2);  xacc1 += __shfl_xor(xacc1, 2);  xacc2 += __shfl_xor(xacc2, 2);
    xacc0 += __shfl_xor(xacc0, 4);  xacc1 += __shfl_xor(xacc1, 4);  xacc2 += __shfl_xor(xacc2, 4);
    xacc0 += __shfl_xor(xacc0, 8);  xacc1 += __shfl_xor(xacc1, 8);  xacc2 += __shfl_xor(xacc2, 8);
    xacc0 += __shfl_xor(xacc0, 16); xacc1 += __shfl_xor(xacc1, 16); xacc2 += __shfl_xor(xacc2, 16);
    xacc0 += __shfl_xor(xacc0, 32); xacc1 += __shfl_xor(xacc1, 32); xacc2 += __shfl_xor(xacc2, 32);
    if ((t & 63) == 0) { xw[t >> 6][0] = xacc0; xw[t >> 6][1] = xacc1; xw[t >> 6][2] = xacc2; }
    __syncthreads();

    const float lm = ligand_mask[b*NL + i];
    if (t < HF) {
        float s = 0.f;
        #pragma unroll
        for (int r = 0; r < 8; ++r) s += hred[r*HF + t];
        out[(size_t)(b*NL + i)*HF + t] = s * 0.01f * lm;
    }
    if (t < 3) {
        float s = xw[0][t] + xw[1][t] + xw[2][t] + xw[3][t];
        out[(size_t)NBATCH*NL*HF + (b*NL + i)*3 + t] = s * 0.01f * lm;
    }
}

extern "C" void kernel_launch(void* const* d_in, const int* in_sizes, int n_in,
                              void* d_out, int out_size, void* d_ws, size_t ws_size,
                              hipStream_t stream) {
    const float* h_ligand     = (const float*)d_in[0];
    const float* x_ligand     = (const float*)d_in[1];
    const float* h_protein    = (const float*)d_in[2];
    const float* x_protein    = (const float*)d_in[3];
    const float* ligand_mask  = (const float*)d_in[4];
    const float* protein_mask = (const float*)d_in[5];
    const float* aW1 = (const float*)d_in[6];
    const float* ab1 = (const float*)d_in[7];
    const float* aW2 = (const float*)d_in[8];
    const float* ab2 = (const float*)d_in[9];
    const float* aW3 = (const float*)d_in[10];
    const float* ab3 = (const float*)d_in[11];
    const float* vW1 = (const float*)d_in[12];
    const float* vb1 = (const float*)d_in[13];
    const float* vW2 = (const float*)d_in[14];
    const float* vb2 = (const float*)d_in[15];
    const float* cW1 = (const float*)d_in[16];
    const float* cb1 = (const float*)d_in[17];
    const float* cW2 = (const float*)d_in[18];
    const float* cb2 = (const float*)d_in[19];

    float* ws = (float*)d_ws;
    float* Al = ws;                       // 512*128
    float* Ap = Al + 512*HF;              // 4096*128
    float* Vp = Ap + 4096*HF;             // 4096*128
    float* Cl = Vp + 4096*HF;             // 512*128
    float* Cp = Cl + 512*HF;              // 4096*128   (total ~6.8 MB)

    precompute_kernel<<<1664, 128, 0, stream>>>(
        h_ligand, h_protein, aW1, ab1, vW1, vb1, cW1, cb1, Al, Ap, Vp, Cl, Cp);

    egnn_main_kernel<<<NBATCH*NL, 256, 0, stream>>>(
        x_ligand, x_protein, ligand_mask, protein_mask,
        aW1, aW2, ab2, aW3, ab3, vW1, vW2, vb2, cW1, cW2, cb2,
        Al, Ap, Vp, Cl, Cp, (float*)d_out);
}

// Round 2
// 250.041 us; speedup vs baseline: 3.6858x; 3.6858x over previous
//
#include <hip/hip_runtime.h>
#include <hip/hip_bf16.h>
#include <math.h>

#define HF 128
#define NL 128
#define NP 1024
#define NB 4
#define EPSF 1e-8f

typedef short bf16x8 __attribute__((ext_vector_type(8)));
typedef float f32x4 __attribute__((ext_vector_type(4)));

__device__ __forceinline__ float fast_rcp(float x) { return __builtin_amdgcn_rcpf(x); }
__device__ __forceinline__ float silu_f(float x)   { return x * fast_rcp(1.0f + __expf(-x)); }
__device__ __forceinline__ float sigmoid_f(float x){ return fast_rcp(1.0f + __expf(-x)); }
__device__ __forceinline__ float tanh_f(float x)   { return 1.0f - 2.0f * fast_rcp(1.0f + __expf(2.0f*x)); }

__device__ __forceinline__ unsigned short f2bf(float f) {
    __hip_bfloat16 h = __float2bfloat16(f);
    return *reinterpret_cast<unsigned short*>(&h);
}

// ---------------------------------------------------------------------------
// Precompute per-node first-layer projections (unchanged from round 1):
//   Al = h_ligand @ aW1[0:128] + ab1 ; Ap = h_protein @ aW1[128:256]
//   Vp = h_protein @ vW1[0:128] + vb1
//   Cl = h_ligand @ cW1[0:128] + cb1 ; Cp = h_protein @ cW1[128:256]
// ---------------------------------------------------------------------------
__global__ __launch_bounds__(128) void precompute_kernel(
    const float* __restrict__ h_ligand, const float* __restrict__ h_protein,
    const float* __restrict__ aW1, const float* __restrict__ ab1,
    const float* __restrict__ vW1, const float* __restrict__ vb1,
    const float* __restrict__ cW1, const float* __restrict__ cb1,
    float* __restrict__ Al, float* __restrict__ Ap, float* __restrict__ Vp,
    float* __restrict__ Cl, float* __restrict__ Cp)
{
    const int blk = blockIdx.x;
    const int n = threadIdx.x;
    const float* in; const float* W; const float* bias; float* out; int r0;
    if (blk < 64)        { r0 = blk*8;        in = h_ligand;  W = aW1;         bias = ab1;     out = Al; }
    else if (blk < 576)  { r0 = (blk-64)*8;   in = h_protein; W = aW1 + HF*HF; bias = nullptr; out = Ap; }
    else if (blk < 1088) { r0 = (blk-576)*8;  in = h_protein; W = vW1;         bias = vb1;     out = Vp; }
    else if (blk < 1152) { r0 = (blk-1088)*8; in = h_ligand;  W = cW1;         bias = cb1;     out = Cl; }
    else                 { r0 = (blk-1152)*8; in = h_protein; W = cW1 + HF*HF; bias = nullptr; out = Cp; }

    __shared__ float rows[8][HF];
    for (int idx = n; idx < 8*HF; idx += 128) rows[idx >> 7][idx & 127] = in[r0*HF + idx];
    __syncthreads();

    const float bv = bias ? bias[n] : 0.0f;
    float acc[8];
    #pragma unroll
    for (int r = 0; r < 8; ++r) acc[r] = bv;
    #pragma unroll 4
    for (int k = 0; k < HF; ++k) {
        float w = W[k*HF + n];
        #pragma unroll
        for (int r = 0; r < 8; ++r) acc[r] = fmaf(rows[r][k], w, acc[r]);
    }
    #pragma unroll
    for (int r = 0; r < 8; ++r) out[(r0 + r)*HF + n] = acc[r];
}

// ---------------------------------------------------------------------------
// Main fused kernel (MFMA): one block per (b,i); 256 threads = 4 waves
// arranged 2(j) x 2(n).  Weights (aW2^T, vW2^T) in bf16 registers.
// Per 32-j tile: build bf16 A tile -> MFMA -> attn ; build V tile -> MFMA
// -> h accumulate.  c-branch stays VALU and overlaps the MFMAs.
// ---------------------------------------------------------------------------
__global__ __launch_bounds__(256, 2) void egnn_main_kernel(
    const float* __restrict__ x_ligand, const float* __restrict__ x_protein,
    const float* __restrict__ ligand_mask, const float* __restrict__ protein_mask,
    const float* __restrict__ aW1, const float* __restrict__ aW2,
    const float* __restrict__ ab2, const float* __restrict__ aW3, const float* __restrict__ ab3,
    const float* __restrict__ vW1, const float* __restrict__ vW2, const float* __restrict__ vb2,
    const float* __restrict__ cW1, const float* __restrict__ cW2, const float* __restrict__ cb2,
    const float* __restrict__ Al, const float* __restrict__ Ap, const float* __restrict__ Vp,
    const float* __restrict__ Cl, const float* __restrict__ Cp,
    float* __restrict__ out)
{
    __shared__ __align__(16) char smem[65536];

    const int t = threadIdx.x;
    const int bi = blockIdx.x;
    const int b = bi >> 7, i = bi & (NL - 1);

    const int lane = t & 63;
    const int wave = t >> 6;
    const int wj = wave >> 1, wn = wave & 1;   // wave tile coords: j-half, n-half
    const int lr = lane & 15, lg = lane >> 4;

    // ---- stage aW2^T, vW2^T into LDS as bf16, XOR-swizzled ----
    // WaT: smem[0..32768), WvT: smem[32768..65536).  Row n (256B), col k.
    for (int it = 0; it < 8; ++it) {
        int task = it*256 + t;
        int n = task & 127, kc = task >> 7;    // kc: 16-byte chunk of k (8 bf16)
        bf16x8 pa, pv;
        #pragma unroll
        for (int q = 0; q < 8; ++q) {
            pa[q] = (short)f2bf(aW2[(kc*8 + q)*HF + n]);
            pv[q] = (short)f2bf(vW2[(kc*8 + q)*HF + n]);
        }
        int boff = n*256 + ((kc*16) ^ ((n & 7) << 4));
        *(bf16x8*)(smem + boff)          = pa;
        *(bf16x8*)(smem + 32768 + boff)  = pv;
    }
    __syncthreads();

    // ---- load B-fragments (weights) into registers, held whole kernel ----
    // B-frag for 16x16x32: lane holds col n = l&15, k = (l>>4)*8 + [0..8)
    bf16x8 wa[4][4], wv[4][4];
    #pragma unroll
    for (int nt = 0; nt < 4; ++nt) {
        int ncol = wn*64 + nt*16 + lr;
        int rb = ncol*256, sw = (ncol & 7) << 4;
        #pragma unroll
        for (int ks = 0; ks < 4; ++ks) {
            int boff = rb + ((lg*16 + ks*64) ^ sw);
            wa[nt][ks] = *(bf16x8*)(smem + boff);
            wv[nt][ks] = *(bf16x8*)(smem + 32768 + boff);
        }
    }
    __syncthreads();

    // ---- carve main-phase LDS from the (now free) staging area ----
    float* ds_all = (float*)(smem + 8192);     // [1024]
    float* pme    = (float*)(smem + 12288);    // [1024] protein_mask * edge
    float* dirx   = (float*)(smem + 16384);    // [1024]
    float* diry   = (float*)(smem + 20480);
    float* dirz   = (float*)(smem + 24576);
    float* Al_s   = (float*)(smem + 28672);    // [128]
    float* Cl_s   = (float*)(smem + 29184);
    float* aw1l   = (float*)(smem + 29696);
    float* cw1l   = (float*)(smem + 30208);
    float* vw1l   = (float*)(smem + 30720);
    float* cW2s   = (float*)(smem + 31232);
    float* attn_part = (float*)(smem + 31744); // [64] = [wn][32]
    float* attn_e = (float*)(smem + 32000);    // [32]
    float* hred   = (float*)(smem + 32768);    // [2][128]
    float* xw     = (float*)(smem + 33792);    // [4][3]
    // tile (bf16 [32][128], swizzled) lives at smem[0..8192)

    const float xl0 = x_ligand[(b*NL + i)*3 + 0];
    const float xl1 = x_ligand[(b*NL + i)*3 + 1];
    const float xl2 = x_ligand[(b*NL + i)*3 + 2];
    const float* xp_b = x_protein + (size_t)b*NP*3;
    const float* pm_b = protein_mask + (size_t)b*NP;

    for (int jj = t; jj < NP; jj += 256) {
        float r0 = xl0 - xp_b[jj*3 + 0];
        float r1 = xl1 - xp_b[jj*3 + 1];
        float r2 = xl2 - xp_b[jj*3 + 2];
        float ds = r0*r0 + r1*r1 + r2*r2;
        float dist = sqrtf(ds + EPSF);
        float e = dist < 10.0f ? 1.0f : 0.0f;
        float inv = fast_rcp(dist + EPSF);
        ds_all[jj] = ds;
        pme[jj]  = pm_b[jj] * e;
        dirx[jj] = r0*inv; diry[jj] = r1*inv; dirz[jj] = r2*inv;
    }
    if (t < 128) {
        Al_s[t] = Al[(b*NL + i)*HF + t];
        Cl_s[t] = Cl[(b*NL + i)*HF + t];
        aw1l[t] = aW1[256*HF + t];
        cw1l[t] = cW1[256*HF + t];
        vw1l[t] = vW1[128*HF + t];
        cW2s[t] = cW2[t];
    }
    // per-lane epilogue constants
    float ab2v[4], aw3v[4], vb2v[4];
    #pragma unroll
    for (int nt = 0; nt < 4; ++nt) {
        int n = wn*64 + nt*16 + lr;
        ab2v[nt] = ab2[n]; aw3v[nt] = aW3[n]; vb2v[nt] = vb2[n];
    }
    const float ab3v = ab3[0], cb2v = cb2[0];
    const float* Ap_b = Ap + (size_t)b*NP*HF;
    const float* Cp_b = Cp + (size_t)b*NP*HF;
    const float* Vp_b = Vp + (size_t)b*NP*HF;

    float hacc[4] = {0.f, 0.f, 0.f, 0.f};
    float xa0 = 0.f, xa1 = 0.f, xa2 = 0.f;
    const int cj = t >> 3, cg = t & 7;         // c-branch mapping
    const int brow = t >> 4, bcol = (t & 15)*8; // tile-build mapping

    __syncthreads();

    for (int jt = 0; jt < 32; ++jt) {
        const int j0 = jt*32;

        // ---- build A tile: silu(Al_i + Ap[j] + ds*aw1_last) -> bf16 ----
        #pragma unroll
        for (int m = 0; m < 2; ++m) {
            int row = m*16 + brow;
            int j = j0 + row;
            float dsv = ds_all[j];
            f32x4 ap0 = *(const f32x4*)&Ap_b[j*HF + bcol];
            f32x4 ap1 = *(const f32x4*)&Ap_b[j*HF + bcol + 4];
            f32x4 al0 = *(const f32x4*)&Al_s[bcol];
            f32x4 al1 = *(const f32x4*)&Al_s[bcol + 4];
            f32x4 w0  = *(const f32x4*)&aw1l[bcol];
            f32x4 w1  = *(const f32x4*)&aw1l[bcol + 4];
            bf16x8 pk;
            #pragma unroll
            for (int q = 0; q < 4; ++q) {
                pk[q]     = (short)f2bf(silu_f(al0[q] + ap0[q] + dsv*w0[q]));
                pk[q + 4] = (short)f2bf(silu_f(al1[q] + ap1[q] + dsv*w1[q]));
            }
            *(bf16x8*)(smem + row*256 + ((bcol*2) ^ ((row & 7) << 4))) = pk;
        }
        __syncthreads();

        // ---- a-GEMM: A-frags from tile, weights from regs ----
        bf16x8 af[4];
        {
            int arow = wj*16 + lr;
            int rb = arow*256, sw = (arow & 7) << 4;
            #pragma unroll
            for (int ks = 0; ks < 4; ++ks)
                af[ks] = *(bf16x8*)(smem + rb + ((lg*16 + ks*64) ^ sw));
        }
        f32x4 acc[4];
        #pragma unroll
        for (int nt = 0; nt < 4; ++nt) {
            acc[nt] = (f32x4){0.f, 0.f, 0.f, 0.f};
            #pragma unroll
            for (int ks = 0; ks < 4; ++ks)
                acc[nt] = __builtin_amdgcn_mfma_f32_16x16x32_bf16(af[ks], wa[nt][ks], acc[nt], 0, 0, 0);
        }

        // ---- c-branch (VALU, overlaps the MFMAs above) ----
        {
            int j = j0 + cj;
            float dsv = ds_all[j];
            float part = 0.f;
            const float* cp = &Cp_b[j*HF + cg*16];
            #pragma unroll
            for (int qq = 0; qq < 4; ++qq) {
                f32x4 c4  = *(const f32x4*)&cp[qq*4];
                f32x4 cl4 = *(const f32x4*)&Cl_s[cg*16 + qq*4];
                f32x4 cw4 = *(const f32x4*)&cw1l[cg*16 + qq*4];
                f32x4 w24 = *(const f32x4*)&cW2s[cg*16 + qq*4];
                #pragma unroll
                for (int q2 = 0; q2 < 4; ++q2) {
                    float pre = cl4[q2] + c4[q2] + dsv*cw4[q2];
                    part += silu_f(pre) * w24[q2];
                }
            }
            part += __shfl_xor(part, 1);
            part += __shfl_xor(part, 2);
            part += __shfl_xor(part, 4);
            if (cg == 0) {
                float cw = tanh_f(part + cb2v) * pme[j];
                xa0 = fmaf(dirx[j], cw, xa0);
                xa1 = fmaf(diry[j], cw, xa1);
                xa2 = fmaf(dirz[j], cw, xa2);
            }
        }

        // ---- a epilogue: silu(a2+ab2) . aW3, reduce over n ----
        #pragma unroll
        for (int r = 0; r < 4; ++r) {
            float p = 0.f;
            #pragma unroll
            for (int nt = 0; nt < 4; ++nt)
                p += silu_f(acc[nt][r] + ab2v[nt]) * aw3v[nt];
            p += __shfl_xor(p, 1);
            p += __shfl_xor(p, 2);
            p += __shfl_xor(p, 4);
            p += __shfl_xor(p, 8);
            if (lr == 0) attn_part[wn*32 + wj*16 + lg*4 + r] = p;
        }
        __syncthreads();

        // ---- attn_e (t<32) and V-tile build (all threads) ----
        if (t < 32) {
            int j = j0 + t;
            attn_e[t] = sigmoid_f(attn_part[t] + attn_part[32 + t] + ab3v) * pme[j];
        }
        #pragma unroll
        for (int m = 0; m < 2; ++m) {
            int row = m*16 + brow;
            int j = j0 + row;
            float dsv = ds_all[j];
            f32x4 vp0 = *(const f32x4*)&Vp_b[j*HF + bcol];
            f32x4 vp1 = *(const f32x4*)&Vp_b[j*HF + bcol + 4];
            f32x4 w0  = *(const f32x4*)&vw1l[bcol];
            f32x4 w1  = *(const f32x4*)&vw1l[bcol + 4];
            bf16x8 pk;
            #pragma unroll
            for (int q = 0; q < 4; ++q) {
                pk[q]     = (short)f2bf(silu_f(vp0[q] + dsv*w0[q]));
                pk[q + 4] = (short)f2bf(silu_f(vp1[q] + dsv*w1[q]));
            }
            *(bf16x8*)(smem + row*256 + ((bcol*2) ^ ((row & 7) << 4))) = pk;
        }
        __syncthreads();

        // ---- v-GEMM + h accumulate ----
        {
            int arow = wj*16 + lr;
            int rb = arow*256, sw = (arow & 7) << 4;
            #pragma unroll
            for (int ks = 0; ks < 4; ++ks)
                af[ks] = *(bf16x8*)(smem + rb + ((lg*16 + ks*64) ^ sw));
        }
        #pragma unroll
        for (int nt = 0; nt < 4; ++nt) {
            acc[nt] = (f32x4){0.f, 0.f, 0.f, 0.f};
            #pragma unroll
            for (int ks = 0; ks < 4; ++ks)
                acc[nt] = __builtin_amdgcn_mfma_f32_16x16x32_bf16(af[ks], wv[nt][ks], acc[nt], 0, 0, 0);
        }
        #pragma unroll
        for (int r = 0; r < 4; ++r) {
            float ae = attn_e[wj*16 + lg*4 + r];
            #pragma unroll
            for (int nt = 0; nt < 4; ++nt)
                hacc[nt] = fmaf(ae, acc[nt][r] + vb2v[nt], hacc[nt]);
        }
        __syncthreads();
    }

    // ---- final reductions ----
    #pragma unroll
    for (int nt = 0; nt < 4; ++nt) {
        hacc[nt] += __shfl_xor(hacc[nt], 16);
        hacc[nt] += __shfl_xor(hacc[nt], 32);
    }
    if (lg == 0) {
        #pragma unroll
        for (int nt = 0; nt < 4; ++nt)
            hred[wj*128 + wn*64 + nt*16 + lr] = hacc[nt];
    }

    xa0 += __shfl_xor(xa0, 1);  xa1 += __shfl_xor(xa1, 1);  xa2 += __shfl_xor(xa2, 1);
    xa0 += __shfl_xor(xa0, 2);  xa1 += __shfl_xor(xa1, 2);  xa2 += __shfl_xor(xa2, 2);
    xa0 += __shfl_xor(xa0, 4);  xa1 += __shfl_xor(xa1, 4);  xa2 += __shfl_xor(xa2, 4);
    xa0 += __shfl_xor(xa0, 8);  xa1 += __shfl_xor(xa1, 8);  xa2 += __shfl_xor(xa2, 8);
    xa0 += __shfl_xor(xa0, 16); xa1 += __shfl_xor(xa1, 16); xa2 += __shfl_xor(xa2, 16);
    xa0 += __shfl_xor(xa0, 32); xa1 += __shfl_xor(xa1, 32); xa2 += __shfl_xor(xa2, 32);
    if (lane == 0) { xw[wave*3 + 0] = xa0; xw[wave*3 + 1] = xa1; xw[wave*3 + 2] = xa2; }
    __syncthreads();

    const float lm = ligand_mask[b*NL + i];
    if (t < 128) {
        out[(size_t)(b*NL + i)*HF + t] = (hred[t] + hred[128 + t]) * 0.01f * lm;
    }
    if (t < 3) {
        float s = xw[t] + xw[3 + t] + xw[6 + t] + xw[9 + t];
        out[(size_t)NB*NL*HF + (b*NL + i)*3 + t] = s * 0.01f * lm;
    }
}

extern "C" void kernel_launch(void* const* d_in, const int* in_sizes, int n_in,
                              void* d_out, int out_size, void* d_ws, size_t ws_size,
                              hipStream_t stream) {
    const float* h_ligand     = (const float*)d_in[0];
    const float* x_ligand     = (const float*)d_in[1];
    const float* h_protein    = (const float*)d_in[2];
    const float* x_protein    = (const float*)d_in[3];
    const float* ligand_mask  = (const float*)d_in[4];
    const float* protein_mask = (const float*)d_in[5];
    const float* aW1 = (const float*)d_in[6];
    const float* ab1 = (const float*)d_in[7];
    const float* aW2 = (const float*)d_in[8];
    const float* ab2 = (const float*)d_in[9];
    const float* aW3 = (const float*)d_in[10];
    const float* ab3 = (const float*)d_in[11];
    const float* vW1 = (const float*)d_in[12];
    const float* vb1 = (const float*)d_in[13];
    const float* vW2 = (const float*)d_in[14];
    const float* vb2 = (const float*)d_in[15];
    const float* cW1 = (const float*)d_in[16];
    const float* cb1 = (const float*)d_in[17];
    const float* cW2 = (const float*)d_in[18];
    const float* cb2 = (const float*)d_in[19];

    float* ws = (float*)d_ws;
    float* Al = ws;                       // 512*128
    float* Ap = Al + 512*HF;              // 4096*128
    float* Vp = Ap + 4096*HF;             // 4096*128
    float* Cl = Vp + 4096*HF;             // 512*128
    float* Cp = Cl + 512*HF;              // 4096*128

    precompute_kernel<<<1664, 128, 0, stream>>>(
        h_ligand, h_protein, aW1, ab1, vW1, vb1, cW1, cb1, Al, Ap, Vp, Cl, Cp);

    egnn_main_kernel<<<NB*NL, 256, 0, stream>>>(
        x_ligand, x_protein, ligand_mask, protein_mask,
        aW1, aW2, ab2, aW3, ab3, vW1, vW2, vb2, cW1, cW2, cb2,
        Al, Ap, Vp, Cl, Cp, (float*)d_out);
}